// Round 7
// baseline (124.222 us; speedup 1.0000x reference)
//
#include <hip/hip_runtime.h>

// UPCLoss, algebraically reduced:
//   N^2*loss = sum_i u_i*||x_i||^2 - 2 * sum_{c,k} W[c][k]*S[c][k]
//   W[c][k] = sum_i G2[i][c] * x[i][k]      (G2 = mask^2 table, 512x16)
//   S[c][k] = sum_{j: label_j=c} x[j][k]
//   u_i     = sum_c cnt[c]*G2[i][c] + H[label_i],  H[c] = sum_i G2[i][c]
// One streaming pass over X (128 MB) instead of the 512x512 Gram matrix.

constexpr int NROW = 512;
constexpr int KDIM = 65536;

// ---------- prep: build G2 (512x16), utab (512 x {u, label}) ----------
__global__ __launch_bounds__(512) void prep_kernel(const int* __restrict__ ranking,
                                                   const int* __restrict__ choice,
                                                   const int* __restrict__ ncp,
                                                   float* __restrict__ g2,
                                                   float2* __restrict__ utab) {
    __shared__ float Hs[16];
    __shared__ int   cnt[16];
    int i = threadIdx.x;
    if (i < 16) { Hs[i] = 0.f; cnt[i] = 0; }
    __syncthreads();

    int rk[16];
#pragma unroll
    for (int q = 0; q < 16; ++q) rk[q] = ranking[i * 16 + q];
    int pos[16];
#pragma unroll
    for (int q = 0; q < 16; ++q) pos[rk[q]] = q;

    int   lbl = rk[0];
    float c   = (float)choice[i];
    float nc  = (float)(*ncp);
    atomicAdd(&cnt[lbl], 1);

    float grow[16];
#pragma unroll
    for (int q = 0; q < 16; ++q) {
        float r = (float)pos[q];
        float m = (r < c) ? (1.f - r / c) : (-(r - c + 1.f) / (nc - c));
        grow[q] = m * m;
        g2[i * 16 + q] = grow[q];
        atomicAdd(&Hs[q], grow[q]);   // 16 banks in parallel, ~512 cyc worst
    }
    __syncthreads();

    float u = 0.f;
#pragma unroll
    for (int q = 0; q < 16; ++q) u += (float)cnt[q] * grow[q];
    u += Hs[lbl];
    utab[i] = make_float2(u, __int_as_float(lbl));
}

// ---------- main streaming pass ----------
// 512 blocks x 256 threads. Block b owns columns [b*128, b*128+128).
// Threads t<128 accumulate rows 0..255, t>=128 rows 256..511 (same cols);
// halves combined via LDS before the bilinear cross term.
__global__ __launch_bounds__(256, 2) void colpass(const float* __restrict__ X,
                                                  const float* __restrict__ g2,
                                                  const float2* __restrict__ utab,
                                                  float* __restrict__ acc) {
    __shared__ float xch[128][33];   // +1 pad: avoid 64-way bank conflict
    __shared__ float red[8];

    int t = threadIdx.x;
    int k = blockIdx.x * 128 + (t & 127);
    // readfirstlane: provably wave-uniform -> g2/utab loads scalarize (s_load)
    int row0 = __builtin_amdgcn_readfirstlane((t >> 7) * 256);
    const float* xp = X + (size_t)row0 * KDIM + k;

    float w[16] = {};
    float s[16] = {};
    float t1 = 0.f;

#pragma unroll 4
    for (int r = 0; r < 256; ++r) {
        float x = xp[(size_t)r * KDIM];
        int row = row0 + r;                      // block... wave-uniform
        float2 ul = utab[row];
        int lbl = __float_as_int(ul.y);
        const float4* g4 = reinterpret_cast<const float4*>(g2 + row * 16);
        float4 ga = g4[0], gb = g4[1], gc = g4[2], gd = g4[3];

        w[0]  = fmaf(ga.x, x, w[0]);  w[1]  = fmaf(ga.y, x, w[1]);
        w[2]  = fmaf(ga.z, x, w[2]);  w[3]  = fmaf(ga.w, x, w[3]);
        w[4]  = fmaf(gb.x, x, w[4]);  w[5]  = fmaf(gb.y, x, w[5]);
        w[6]  = fmaf(gb.z, x, w[6]);  w[7]  = fmaf(gb.w, x, w[7]);
        w[8]  = fmaf(gc.x, x, w[8]);  w[9]  = fmaf(gc.y, x, w[9]);
        w[10] = fmaf(gc.z, x, w[10]); w[11] = fmaf(gc.w, x, w[11]);
        w[12] = fmaf(gd.x, x, w[12]); w[13] = fmaf(gd.y, x, w[13]);
        w[14] = fmaf(gd.z, x, w[14]); w[15] = fmaf(gd.w, x, w[15]);

        switch (lbl) {   // lbl is wave-uniform: scalar branch, one add executes
            case 0:  s[0]  += x; break;
            case 1:  s[1]  += x; break;
            case 2:  s[2]  += x; break;
            case 3:  s[3]  += x; break;
            case 4:  s[4]  += x; break;
            case 5:  s[5]  += x; break;
            case 6:  s[6]  += x; break;
            case 7:  s[7]  += x; break;
            case 8:  s[8]  += x; break;
            case 9:  s[9]  += x; break;
            case 10: s[10] += x; break;
            case 11: s[11] += x; break;
            case 12: s[12] += x; break;
            case 13: s[13] += x; break;
            case 14: s[14] += x; break;
            default: s[15] += x; break;
        }
        t1 = fmaf(ul.x, x * x, t1);
    }

    // combine the two row-halves for this column, then cross = sum_c W*S
    if (t < 128) {
#pragma unroll
        for (int c = 0; c < 16; ++c) { xch[t][c] = w[c]; xch[t][16 + c] = s[c]; }
    }
    __syncthreads();
    float cp = 0.f;
    if (t >= 128) {
        int p = t - 128;
#pragma unroll
        for (int c = 0; c < 16; ++c) {
            float wt = w[c] + xch[p][c];
            float st = s[c] + xch[p][16 + c];
            cp = fmaf(wt, st, cp);
        }
    }

    // block-reduce cp and t1
#pragma unroll
    for (int off = 32; off > 0; off >>= 1) {
        cp += __shfl_down(cp, off);
        t1 += __shfl_down(t1, off);
    }
    int wv = t >> 6;
    if ((t & 63) == 0) { red[wv] = cp; red[4 + wv] = t1; }
    __syncthreads();
    if (t == 0) {
        atomicAdd(&acc[1], red[0] + red[1] + red[2] + red[3]);
        atomicAdd(&acc[0], red[4] + red[5] + red[6] + red[7]);
    }
}

__global__ void finalize(const float* __restrict__ acc, float* __restrict__ out) {
    out[0] = (acc[0] - 2.f * acc[1]) * (1.f / ((float)NROW * (float)NROW));
}

extern "C" void kernel_launch(void* const* d_in, const int* in_sizes, int n_in,
                              void* d_out, int out_size, void* d_ws, size_t ws_size,
                              hipStream_t stream) {
    const float* X       = (const float*)d_in[0];
    const int*   ranking = (const int*)d_in[1];
    const int*   choice  = (const int*)d_in[2];
    const int*   ncp     = (const int*)d_in[3];
    float*       ws      = (float*)d_ws;

    // ws layout: acc[2] f32 | (pad to 16B) g2[512*16] f32 | utab[512] float2
    float*  acc  = ws;
    float*  g2   = ws + 4;
    float2* utab = (float2*)(ws + 4 + NROW * 16);

    hipMemsetAsync(acc, 0, 2 * sizeof(float), stream);
    prep_kernel<<<dim3(1), dim3(512), 0, stream>>>(ranking, choice, ncp, g2, utab);
    colpass<<<dim3(512), dim3(256), 0, stream>>>(X, g2, utab, acc);
    finalize<<<dim3(1), dim3(1), 0, stream>>>(acc, (float*)d_out);
}

// Round 8
// 104.962 us; speedup vs baseline: 1.1835x; 1.1835x over previous
//
#include <hip/hip_runtime.h>

// UPCLoss, algebraically reduced (validated in R7, absmax 0.0):
//   N^2*loss = sum_i u_i*||x_i||^2 - 2 * sum_{c,k} W[c][k]*S[c][k]
//   W[c][k] = sum_i G2[i][c] * x[i][k]      (G2 = mask^2 table, 512x16)
//   S[c][k] = sum_j onehot[j][c] * x[j][k]
//   u_i     = sum_c cnt[c]*G2[i][c] + H[label_i],  H[c] = sum_i G2[i][c]
// One streaming pass over X. R7 failed on latency (switch broke pipelining,
// 8 waves/CU): this version is straight-line one-hot FMA + 16 waves/CU.

constexpr int NROW = 512;
constexpr int KDIM = 65536;

// ---------- prep: g2x[512][32] = [w-coeffs | one-hot], utab[512] = u ----------
__global__ __launch_bounds__(512) void prep_kernel(const int* __restrict__ ranking,
                                                   const int* __restrict__ choice,
                                                   const int* __restrict__ ncp,
                                                   float* __restrict__ g2x,
                                                   float* __restrict__ utab) {
    __shared__ float Hs[16];
    __shared__ int   cnt[16];
    int i = threadIdx.x;
    if (i < 16) { Hs[i] = 0.f; cnt[i] = 0; }
    __syncthreads();

    int rk[16];
#pragma unroll
    for (int q = 0; q < 16; ++q) rk[q] = ranking[i * 16 + q];
    int pos[16];
#pragma unroll
    for (int q = 0; q < 16; ++q) pos[rk[q]] = q;

    int   lbl = rk[0];
    float c   = (float)choice[i];
    float nc  = (float)(*ncp);
    atomicAdd(&cnt[lbl], 1);

    float grow[16];
#pragma unroll
    for (int q = 0; q < 16; ++q) {
        float r = (float)pos[q];
        float m = (r < c) ? (1.f - r / c) : (-(r - c + 1.f) / (nc - c));
        grow[q] = m * m;
        g2x[i * 32 + q]      = grow[q];
        g2x[i * 32 + 16 + q] = (q == lbl) ? 1.f : 0.f;
        atomicAdd(&Hs[q], grow[q]);
    }
    __syncthreads();

    float u = 0.f;
#pragma unroll
    for (int q = 0; q < 16; ++q) u += (float)cnt[q] * grow[q];
    u += Hs[lbl];
    utab[i] = u;
}

// ---------- main streaming pass ----------
// 1024 blocks x 256 threads; wave q of block b owns cols [b*64, b*64+64),
// rows [q*128, q*128+128). Row-quarters combined via LDS (stride 33: no
// bank conflicts), then cross = sum_c W*S per column.
__global__ __launch_bounds__(256, 4) void colpass(const float* __restrict__ X,
                                                  const float* __restrict__ g2x,
                                                  const float* __restrict__ utab,
                                                  float* __restrict__ acc) {
    __shared__ float xch[4][64][33];
    __shared__ float red[4];

    int t    = threadIdx.x;
    int lane = t & 63;
    int q    = __builtin_amdgcn_readfirstlane(t >> 6);   // wave-uniform quarter
    int col  = blockIdx.x * 64 + lane;
    const float* xp = X + (size_t)(q * 128) * KDIM + col;

    float w[16] = {};
    float s[16] = {};
    float t1 = 0.f;

#pragma unroll 8
    for (int r = 0; r < 128; ++r) {
        float x = xp[(size_t)r * KDIM];
        int row = q * 128 + r;                            // wave-uniform
        const float4* gp = reinterpret_cast<const float4*>(g2x + (size_t)row * 32);
        float4 ga = gp[0], gb = gp[1], gc = gp[2], gd = gp[3];   // w coeffs
        float4 ea = gp[4], eb = gp[5], ec = gp[6], ed = gp[7];   // one-hot
        float  u  = utab[row];

        w[0]  = fmaf(ga.x, x, w[0]);  w[1]  = fmaf(ga.y, x, w[1]);
        w[2]  = fmaf(ga.z, x, w[2]);  w[3]  = fmaf(ga.w, x, w[3]);
        w[4]  = fmaf(gb.x, x, w[4]);  w[5]  = fmaf(gb.y, x, w[5]);
        w[6]  = fmaf(gb.z, x, w[6]);  w[7]  = fmaf(gb.w, x, w[7]);
        w[8]  = fmaf(gc.x, x, w[8]);  w[9]  = fmaf(gc.y, x, w[9]);
        w[10] = fmaf(gc.z, x, w[10]); w[11] = fmaf(gc.w, x, w[11]);
        w[12] = fmaf(gd.x, x, w[12]); w[13] = fmaf(gd.y, x, w[13]);
        w[14] = fmaf(gd.z, x, w[14]); w[15] = fmaf(gd.w, x, w[15]);

        s[0]  = fmaf(ea.x, x, s[0]);  s[1]  = fmaf(ea.y, x, s[1]);
        s[2]  = fmaf(ea.z, x, s[2]);  s[3]  = fmaf(ea.w, x, s[3]);
        s[4]  = fmaf(eb.x, x, s[4]);  s[5]  = fmaf(eb.y, x, s[5]);
        s[6]  = fmaf(eb.z, x, s[6]);  s[7]  = fmaf(eb.w, x, s[7]);
        s[8]  = fmaf(ec.x, x, s[8]);  s[9]  = fmaf(ec.y, x, s[9]);
        s[10] = fmaf(ec.z, x, s[10]); s[11] = fmaf(ec.w, x, s[11]);
        s[12] = fmaf(ed.x, x, s[12]); s[13] = fmaf(ed.y, x, s[13]);
        s[14] = fmaf(ed.z, x, s[14]); s[15] = fmaf(ed.w, x, s[15]);

        t1 = fmaf(u, x * x, t1);
    }

    // stage this quarter's w|s (stride 33 floats -> 64 lanes hit distinct banks)
#pragma unroll
    for (int v = 0; v < 16; ++v) {
        xch[q][lane][v]      = w[v];
        xch[q][lane][16 + v] = s[v];
    }
    // t1: wave reduce, one slot per wave
#pragma unroll
    for (int off = 32; off > 0; off >>= 1) t1 += __shfl_down(t1, off);
    if (lane == 0) red[q] = t1;
    __syncthreads();

    if (t < 64) {
        float cross = 0.f;
#pragma unroll
        for (int c = 0; c < 16; ++c) {
            float wt = xch[0][t][c] + xch[1][t][c] + xch[2][t][c] + xch[3][t][c];
            float st = xch[0][t][16 + c] + xch[1][t][16 + c]
                     + xch[2][t][16 + c] + xch[3][t][16 + c];
            cross = fmaf(wt, st, cross);
        }
#pragma unroll
        for (int off = 32; off > 0; off >>= 1) cross += __shfl_down(cross, off);
        if (t == 0) {
            atomicAdd(&acc[1], cross);
            atomicAdd(&acc[0], red[0] + red[1] + red[2] + red[3]);
        }
    }
}

__global__ void finalize(const float* __restrict__ acc, float* __restrict__ out) {
    out[0] = (acc[0] - 2.f * acc[1]) * (1.f / ((float)NROW * (float)NROW));
}

extern "C" void kernel_launch(void* const* d_in, const int* in_sizes, int n_in,
                              void* d_out, int out_size, void* d_ws, size_t ws_size,
                              hipStream_t stream) {
    const float* X       = (const float*)d_in[0];
    const int*   ranking = (const int*)d_in[1];
    const int*   choice  = (const int*)d_in[2];
    const int*   ncp     = (const int*)d_in[3];
    float*       ws      = (float*)d_ws;

    // ws layout: acc[2] f32 | pad | g2x[512*32] f32 | utab[512] f32
    float* acc  = ws;
    float* g2x  = ws + 16;
    float* utab = g2x + NROW * 32;

    hipMemsetAsync(acc, 0, 2 * sizeof(float), stream);
    prep_kernel<<<dim3(1), dim3(512), 0, stream>>>(ranking, choice, ncp, g2x, utab);
    colpass<<<dim3(1024), dim3(256), 0, stream>>>(X, g2x, utab, acc);
    finalize<<<dim3(1), dim3(1), 0, stream>>>(acc, (float*)d_out);
}